// Round 7
// baseline (515.666 us; speedup 1.0000x reference)
//
#include <hip/hip_runtime.h>
#include <hip/hip_bf16.h>
#include <stdint.h>

typedef unsigned short u16;
typedef __attribute__((ext_vector_type(8))) short short8;
typedef __attribute__((ext_vector_type(4))) float floatx4;

#define B_   512
#define D_   512
#define C_   100000

#define SCALE_  64.0f
#define COSM_   0.8775825618903728f
#define SINM_   0.479425538604203f
#define TH_     (-0.8775825618903728f)
#define MM_     0.2397127693021015f
#define EPS_    1e-7f
#define SHIFT_  89.6f

#define BM 256
#define BN 64
#define BK 32

__device__ inline float wave_reduce_sum(float v) {
    v += __shfl_xor(v, 1);
    v += __shfl_xor(v, 2);
    v += __shfl_xor(v, 4);
    v += __shfl_xor(v, 8);
    v += __shfl_xor(v, 16);
    v += __shfl_xor(v, 32);
    return v;
}

__device__ inline u16 f2bf(float x) {
    union { float f; uint32_t u; } v; v.f = x;
    uint32_t r = v.u + 0x7fffu + ((v.u >> 16) & 1u);  // RNE
    return (u16)(r >> 16);
}

// RNE pack of two fp32 -> one dword of 2x bf16 (v_cvt_pk_bf16_f32)
__device__ inline uint32_t cvt2_rn(float a, float b) {
    union { __hip_bfloat162 h; uint32_t u; } v;
    v.h = __float22bfloat162_rn(make_float2(a, b));
    return v.u;
}

// Normalize embedding rows -> e_bf16 in MFMA-FRAGMENT-MAJOR layout, per-row
// phi (exact fp32 path), zero-init rowsum.
// A2 layout (bytes): (((b>>6)*16 + kt)*4 + ((b>>4)&3))*1024
//                    + ((oct&3)*16 + (b&15))*16 + half*8
// so that in the GEMM, af[mi] at step kt is 64 lanes x consecutive 16B
// (one dense 1KB burst) instead of 16 scattered 64B segments.
__global__ __launch_bounds__(256) void norm_e_phi_kernel(
    const float* __restrict__ emb, const float* __restrict__ w_raw,
    const int* __restrict__ gt, u16* __restrict__ e_bf16,
    float* __restrict__ phi, float* __restrict__ rowsum) {
    if (threadIdx.x < 4) rowsum[blockIdx.x * 4 + threadIdx.x] = 0.0f;
    int wv = threadIdx.x >> 6;
    int lane = threadIdx.x & 63;
    int b = blockIdx.x * 4 + wv;
    const float4* rp = (const float4*)(emb + (long)b * D_);
    float4 f0 = rp[lane], f1 = rp[lane + 64];
    float sq = f0.x*f0.x + f0.y*f0.y + f0.z*f0.z + f0.w*f0.w
             + f1.x*f1.x + f1.y*f1.y + f1.z*f1.z + f1.w*f1.w;
    sq = wave_reduce_sum(sq);
    float rn = 1.0f / sqrtf(sq);
    f0.x *= rn; f0.y *= rn; f0.z *= rn; f0.w *= rn;
    f1.x *= rn; f1.y *= rn; f1.z *= rn; f1.w *= rn;
    uint2 p0, p1;
    p0.x = (uint32_t)f2bf(f0.x) | ((uint32_t)f2bf(f0.y) << 16);
    p0.y = (uint32_t)f2bf(f0.z) | ((uint32_t)f2bf(f0.w) << 16);
    p1.x = (uint32_t)f2bf(f1.x) | ((uint32_t)f2bf(f1.y) << 16);
    p1.y = (uint32_t)f2bf(f1.z) | ((uint32_t)f2bf(f1.w) << 16);
    // p0 = 4 bf16 at k=4*lane (octet o0=lane>>1, half=lane&1)
    // p1 = 4 bf16 at k=256+4*lane (octet o1=32+(lane>>1) -> +32KB)
    size_t d0 = (size_t)((((b >> 6) * 16 + (lane >> 3)) * 4 + ((b >> 4) & 3))) * 512
              + (size_t)((((lane >> 1) & 3) * 16 + (b & 15)) * 8) + (lane & 1) * 4;
    *(uint2*)(e_bf16 + d0) = p0;
    *(uint2*)(e_bf16 + d0 + 16384) = p1;

    int g = gt[b];
    const float4* wp = (const float4*)(w_raw + (long)g * D_);
    float4 w0 = wp[lane], w1 = wp[lane + 64];
    float dt = f0.x*w0.x + f0.y*w0.y + f0.z*w0.z + f0.w*w0.w
             + f1.x*w1.x + f1.y*w1.y + f1.z*w1.z + f1.w*w1.w;
    float wsq = w0.x*w0.x + w0.y*w0.y + w0.z*w0.z + w0.w*w0.w
              + w1.x*w1.x + w1.y*w1.y + w1.z*w1.z + w1.w*w1.w;
    dt = wave_reduce_sum(dt);
    wsq = wave_reduce_sum(wsq);
    if (lane == 0) {
        float pos = dt / sqrtf(wsq);
        pos = fminf(fmaxf(pos, -1.0f + EPS_), 1.0f - EPS_);
        float s2 = 1.0f - pos * pos;
        s2 = fminf(fmaxf(s2, EPS_), 1.0f - EPS_);
        float sin_t = sqrtf(s2);
        float ph = pos * COSM_ - sin_t * SINM_;
        ph = (pos > TH_) ? ph : (pos - MM_);
        phi[b] = ph;
    }
}

// convert two fp32x4 (two different W rows) to bf16 and store 8B each
__device__ inline void cvt_store2(const float4& a, const float4& b,
                                  u16* dA, u16* dB, float& sqa, float& sqb) {
    uint2 ua; ua.x = cvt2_rn(a.x, a.y); ua.y = cvt2_rn(a.z, a.w);
    uint2 ub; ub.x = cvt2_rn(b.x, b.y); ub.y = cvt2_rn(b.z, b.w);
    *(uint2*)dA = ua;
    *(uint2*)dB = ub;
    sqa += a.x*a.x + a.y*a.y + a.z*a.z + a.w*a.w;
    sqb += b.x*b.x + b.y*b.y + b.z*b.z + b.w*b.w;
}

// GEMM, r6 skeleton with DENSE-COALESCED global patterns:
//  - A fragment-major (see norm kernel): af load = 64 lanes x consecutive
//    16B = one 1KB burst. Was: 16 scattered 64B segments per load.
//  - B staging: lane l loads float4 of row 16wv+(l>>3) at float-offset
//    kt*32+(l&7)*4 (lanes 0-7 = one row's dense 128B window) and the same
//    for row+8. 8 dense 128B segments/load. Was: 16 sparse 64B segments.
//  - LDS layout/swizzle identical to r0 (verified 0 conflicts): 16B unit
//    phys = logical ^ ((row>>1)&3); fragment read = 1 ds_read_b128.
//  - per-row sumsq now reduced in-register over the 8 staging lanes.
//  - 4-deep bv pipeline + lgkm-only barrier kept from r6.
__global__ __launch_bounds__(256, 3) void gemm_arcface_fused(
    const u16* __restrict__ a_g,     // e_bf16 fragment-major [512KB]
    const float* __restrict__ w_g,   // raw weight fp32 [100000][512]
    const float* __restrict__ phi, const int* __restrict__ gt,
    float* __restrict__ rowsum) {
    __shared__ __align__(16) u16 b_tile[2][BN * BK];  // 2 x 4 KB
    __shared__ float phi_s[BM];
    __shared__ int gt_s[BM];
    __shared__ float rnorm_s[BN];

    int tid = threadIdx.x;
    int c0 = (blockIdx.x >> 1) * BN;
    int m0 = (blockIdx.x & 1) * BM;

    phi_s[tid] = phi[m0 + tid];
    gt_s[tid] = gt[m0 + tid];

    int wv = tid >> 6, lane = tid & 63;
    int low4 = lane & 15, quad = lane >> 4;

    // --- B staging (dense): rows rA=16wv+(l>>3) and rA+8 ---
    int rA = wv * 16 + (lane >> 3);
    long growA = min(c0 + rA, C_ - 1);
    long growB = min(c0 + rA + 8, C_ - 1);
    const float4* srcA = (const float4*)(w_g + growA * (long)D_) + (lane & 7);
    const float4* srcB = (const float4*)(w_g + growB * (long)D_) + (lane & 7);
    // key((16wv+x)>>1 &3) == (l>>4)&3 for both rows (x<8, +8 adds 4 -> &3 same)
    int physU = ((lane & 7) >> 1) ^ ((lane >> 4) & 3);
    int stoff = physU * 8 + (lane & 1) * 4;            // u16 units
    u16* dA[2] = { &b_tile[0][rA * 32 + stoff], &b_tile[1][rA * 32 + stoff] };
    u16* dB[2] = { &b_tile[0][(rA + 8) * 32 + stoff], &b_tile[1][(rA + 8) * 32 + stoff] };

    // --- A fragments: dense fragment-major bursts ---
    const u16* a2w = a_g + (size_t)((m0 >> 6) + wv) * 32768;

    // --- fragment read offset (r0's verified scheme) ---
    int lslot = quad ^ ((low4 >> 1) & 3);
    int bf_off = low4 * BK + lslot * 8;

    floatx4 acc[4][4] = {};
    float sqA = 0.0f, sqB = 0.0f;
    float4 bv[4][2];     // 4-deep pipeline: bv[j] holds tile t with t%4==j

    // prologue: tiles 0..3 in flight; tile 0 converted into LDS buf 0
#pragma unroll
    for (int j = 0; j < 4; j++) {
        bv[j][0] = srcA[j * 8];
        bv[j][1] = srcB[j * 8];
    }
    cvt_store2(bv[0][0], bv[0][1], dA[0], dB[0], sqA, sqB);
    asm volatile("s_waitcnt lgkmcnt(0)" ::: "memory");
    __builtin_amdgcn_s_barrier();

#pragma unroll
    for (int kt = 0; kt < 16; kt++) {
        int p = kt & 1;
        if (kt < 12) {   // issue tile kt+4 into the slot freed by tile kt
            bv[kt & 3][0] = srcA[(kt + 4) * 8];
            bv[kt & 3][1] = srcB[(kt + 4) * 8];
        }
        short8 af[4];
#pragma unroll
        for (int mi = 0; mi < 4; mi++)
            af[mi] = *(const short8*)(a2w + ((kt * 4 + mi) << 9) + (lane << 3));
        short8 bf[4];
#pragma unroll
        for (int ni = 0; ni < 4; ni++)
            bf[ni] = *(const short8*)(&b_tile[p][ni * 16 * BK + bf_off]);
#pragma unroll
        for (int mi = 0; mi < 4; mi++)
#pragma unroll
            for (int ni = 0; ni < 4; ni++)
                acc[mi][ni] = __builtin_amdgcn_mfma_f32_16x16x32_bf16(
                    af[mi], bf[ni], acc[mi][ni], 0, 0, 0);
        if (kt < 15)   // convert tile kt+1 into the other LDS buffer
            cvt_store2(bv[(kt + 1) & 3][0], bv[(kt + 1) & 3][1],
                       dA[1 - p], dB[1 - p], sqA, sqB);
        asm volatile("s_waitcnt lgkmcnt(0)" ::: "memory");
        __builtin_amdgcn_s_barrier();
    }

    // per-row 1/||w||: 8 staging lanes of a row hold disjoint k-slices
    sqA += __shfl_xor(sqA, 1); sqA += __shfl_xor(sqA, 2); sqA += __shfl_xor(sqA, 4);
    sqB += __shfl_xor(sqB, 1); sqB += __shfl_xor(sqB, 2); sqB += __shfl_xor(sqB, 4);
    if ((lane & 7) == 0) {
        rnorm_s[rA] = 1.0f / sqrtf(sqA);
        rnorm_s[rA + 8] = 1.0f / sqrtf(sqB);
    }
    __syncthreads();   // outside hot loop

    // epilogue: normalize, clip, reweight, gt-substitute, exp, row-reduce
#pragma unroll
    for (int mi = 0; mi < 4; mi++) {
#pragma unroll
        for (int r = 0; r < 4; r++) {
            int rl = wv * 64 + mi * 16 + quad * 4 + r;
            float ph = phi_s[rl];
            int g = gt_s[rl];
            float s = 0.0f;
#pragma unroll
            for (int ni = 0; ni < 4; ni++) {
                int cl = ni * 16 + low4;
                int c = c0 + cl;
                float v = acc[mi][ni][r] * rnorm_s[cl];
                v = fminf(fmaxf(v, -1.0f + EPS_), 1.0f - EPS_);
                float logit = (v > ph) ? (1.2f * v + 0.2f) : v;
                logit *= SCALE_;
                if (c == g) logit = SCALE_ * ph;
                s += (c < C_) ? __expf(logit - SHIFT_) : 0.0f;
            }
            s += __shfl_xor(s, 1);
            s += __shfl_xor(s, 2);
            s += __shfl_xor(s, 4);
            s += __shfl_xor(s, 8);
            if (low4 == 0) atomicAdd(&rowsum[m0 + rl], s);
        }
    }
}

__global__ __launch_bounds__(256) void loss_kernel(
    const float* __restrict__ rowsum, const float* __restrict__ phi,
    float* __restrict__ out) {
    __shared__ float red[4];
    int tid = threadIdx.x;
    float s = 0.0f;
    for (int b = tid; b < B_; b += 256)
        s += logf(rowsum[b]) + SHIFT_ - SCALE_ * phi[b];
    s = wave_reduce_sum(s);
    int wv = tid >> 6, lane = tid & 63;
    if (lane == 0) red[wv] = s;
    __syncthreads();
    if (tid == 0) out[0] = (red[0] + red[1] + red[2] + red[3]) * (1.0f / B_);
}

extern "C" void kernel_launch(void* const* d_in, const int* in_sizes, int n_in,
                              void* d_out, int out_size, void* d_ws, size_t ws_size,
                              hipStream_t stream) {
    const float* emb = (const float*)d_in[0];   // [512][512] f32
    const float* wgt = (const float*)d_in[1];   // [100000][512] f32
    const int* gt = (const int*)d_in[2];        // [512] int32
    float* out = (float*)d_out;

    char* ws = (char*)d_ws;
    u16* e_bf16 = (u16*)(ws);                   //   524,288 B (fragment-major)
    float* phi = (float*)(ws + 524288);         //     2,048 B
    float* rowsum = (float*)(ws + 526336);      //     2,048 B

    norm_e_phi_kernel<<<B_ / 4, 256, 0, stream>>>(emb, wgt, gt, e_bf16, phi, rowsum);
    int nc = (C_ + BN - 1) / BN;                // 1563 c-tiles
    gemm_arcface_fused<<<nc * 2, 256, 0, stream>>>(e_bf16, wgt, phi, gt, rowsum);
    loss_kernel<<<1, 256, 0, stream>>>(rowsum, phi, out);
}